// Round 4
// baseline (439.191 us; speedup 1.0000x reference)
//
#include <hip/hip_runtime.h>

// BoxCrossAttention: softmax over a length-1 key axis == 1.0, so
// out[b,c,w,h] = 9 * (vp[b] @ Wo + bo)[c],  vp = (mish(y@W1+b1)@W2+b2)[:,512:] @ Wv + bv.
// x / conv / unfold / q / k projections are dead code.
//
// Single persistent kernel, 1024 blocks (co-resident: __launch_bounds__(256,4)
// => 4 blocks/CU * 256 CU). Stages chained with device-scope spin barriers
// (release atomicAdd / acquire poll + __threadfence), per guide §6 G16.
// Counters in d_ws, zeroed by a tiny hipMemsetAsync each call (handles 0xAA
// poison; deterministic). Spin bailout guard prevents hangs on logic bugs.

__device__ __forceinline__ float mishf(float v) {
    float sp = (v > 20.0f) ? v : log1pf(expf(v));
    return v * tanhf(sp);
}

__device__ __forceinline__ void arrive(unsigned* c) {
    __hip_atomic_fetch_add(c, 1u, __ATOMIC_RELEASE, __HIP_MEMORY_SCOPE_AGENT);
}

template <int SLP>
__device__ __forceinline__ void wait_ctr(unsigned* c, unsigned target) {
    int spins = 0;
    while (__hip_atomic_load(c, __ATOMIC_ACQUIRE, __HIP_MEMORY_SCOPE_AGENT) < target) {
        __builtin_amdgcn_s_sleep(SLP);   // SLP must be a literal constant
        if (++spins > (1 << 22)) break;  // safety valve: never hit when logic is right
    }
}

__global__ __launch_bounds__(256, 4) void mega(
    const float* __restrict__ y,  const float* __restrict__ W1, const float* __restrict__ b1,
    const float* __restrict__ W2, const float* __restrict__ b2,
    const float* __restrict__ Wv, const float* __restrict__ bv,
    const float* __restrict__ Wo, const float* __restrict__ bo,
    float* __restrict__ ws, unsigned* __restrict__ ctr, float4* __restrict__ out)
{
    float* hidden = ws;          // 4096 floats
    float* v_raw  = ws + 4096;   // 2048
    float* vp     = ws + 6144;   // 1024
    float* o9     = ws + 7168;   // 1024

    __shared__ float smem[1280]; // aliased per stage (max: 1024+256 in stage B)
    int bi = blockIdx.x, t = threadIdx.x;

    if (bi < 64) {
        // stage A: hidden[b][j] = mish(b1[j] + sum_t y[b][t]*W1[t][j])
        int b = bi >> 4, j0 = (bi & 15) * 64;
        float* y_s = smem, * ps = smem + 256;
        y_s[t] = y[b * 256 + t];
        __syncthreads();
        int col = j0 + (t & 63), kc = t >> 6;
        const float* w  = W1 + (size_t)(kc * 64) * 1024 + col;
        const float* ys = y_s + kc * 64;
        float a0 = 0, a1 = 0, a2 = 0, a3 = 0;
        for (int r = 0; r < 64; r += 4) {
            a0 = fmaf(ys[r + 0], w[(r + 0) * 1024], a0);
            a1 = fmaf(ys[r + 1], w[(r + 1) * 1024], a1);
            a2 = fmaf(ys[r + 2], w[(r + 2) * 1024], a2);
            a3 = fmaf(ys[r + 3], w[(r + 3) * 1024], a3);
        }
        ps[t] = (a0 + a1) + (a2 + a3);
        __syncthreads();
        if (t < 64)
            hidden[b * 1024 + j0 + t] =
                mishf((ps[t] + ps[t + 64]) + (ps[t + 128] + ps[t + 192]) + b1[j0 + t]);
        __threadfence();
        __syncthreads();
        if (t == 0) arrive(&ctr[0]);
    } else if (bi < 192) {
        // stage B: v_raw[b][c] = b2[512+c] + sum_i hidden[b][i]*W2[i][512+c]
        int bj = bi - 64, b = bj >> 5, c0 = (bj & 31) * 16;
        if (t == 0) wait_ctr<2>(&ctr[0], 64);
        __syncthreads();
        __threadfence();
        float* h_s = smem, * ps = smem + 1024;
        h_s[t]       = hidden[b * 1024 + t];
        h_s[t + 256] = hidden[b * 1024 + t + 256];
        h_s[t + 512] = hidden[b * 1024 + t + 512];
        h_s[t + 768] = hidden[b * 1024 + t + 768];
        __syncthreads();
        int col = c0 + (t & 15), kc = t >> 4;
        const float* w  = W2 + (size_t)(kc * 64) * 1024 + 512 + col;
        const float* hs = h_s + kc * 64;
        float a0 = 0, a1 = 0, a2 = 0, a3 = 0;
        for (int r = 0; r < 64; r += 4) {
            a0 = fmaf(hs[r + 0], w[(size_t)(r + 0) * 1024], a0);
            a1 = fmaf(hs[r + 1], w[(size_t)(r + 1) * 1024], a1);
            a2 = fmaf(hs[r + 2], w[(size_t)(r + 2) * 1024], a2);
            a3 = fmaf(hs[r + 3], w[(size_t)(r + 3) * 1024], a3);
        }
        ps[t] = (a0 + a1) + (a2 + a3);
        __syncthreads();
        if (t < 16) {
            float s = 0;
            #pragma unroll
            for (int k = 0; k < 16; ++k) s += ps[t + 16 * k];
            v_raw[b * 512 + c0 + t] = s + b2[512 + c0 + t];
        }
        __threadfence();
        __syncthreads();
        if (t == 0) arrive(&ctr[1]);
    } else if (bi < 224) {
        // stage C: vp[b][d] = bv[d] + sum_i v_raw[b][i]*Wv[i][d]
        int bc = bi - 192, b = bc >> 3, d0 = (bc & 7) * 32;
        if (t == 0) wait_ctr<2>(&ctr[1], 128);
        __syncthreads();
        __threadfence();
        float* v_s = smem, * ps = smem + 512;
        v_s[t]       = v_raw[b * 512 + t];
        v_s[t + 256] = v_raw[b * 512 + t + 256];
        __syncthreads();
        int col = d0 + (t & 31), kc = t >> 5;
        const float* w  = Wv + (size_t)(kc * 64) * 256 + col;
        const float* vs = v_s + kc * 64;
        float a0 = 0, a1 = 0, a2 = 0, a3 = 0;
        for (int r = 0; r < 64; r += 4) {
            a0 = fmaf(vs[r + 0], w[(r + 0) * 256], a0);
            a1 = fmaf(vs[r + 1], w[(r + 1) * 256], a1);
            a2 = fmaf(vs[r + 2], w[(r + 2) * 256], a2);
            a3 = fmaf(vs[r + 3], w[(r + 3) * 256], a3);
        }
        ps[t] = (a0 + a1) + (a2 + a3);
        __syncthreads();
        if (t < 32) {
            float s = 0;
            #pragma unroll
            for (int k = 0; k < 8; ++k) s += ps[t + 32 * k];
            vp[b * 256 + d0 + t] = s + bv[d0 + t];
        }
        __threadfence();
        __syncthreads();
        if (t == 0) arrive(&ctr[2]);
    } else if (bi < 228) {
        // stage D: o9[b][c] = 9*(bo[c] + sum_d vp[b][d]*Wo[d][c])
        int b = bi - 224;
        if (t == 0) wait_ctr<2>(&ctr[2], 32);
        __syncthreads();
        __threadfence();
        float* vp_s = smem;
        vp_s[t] = vp[b * 256 + t];
        __syncthreads();
        const float* w = Wo + t;
        float a0 = 0, a1 = 0, a2 = 0, a3 = 0;
        #pragma unroll 4
        for (int d = 0; d < 256; d += 4) {
            a0 = fmaf(vp_s[d + 0], w[(size_t)(d + 0) * 256], a0);
            a1 = fmaf(vp_s[d + 1], w[(size_t)(d + 1) * 256], a1);
            a2 = fmaf(vp_s[d + 2], w[(size_t)(d + 2) * 256], a2);
            a3 = fmaf(vp_s[d + 3], w[(size_t)(d + 3) * 256], a3);
        }
        o9[b * 256 + t] = 9.0f * (((a0 + a1) + (a2 + a3)) + bo[t]);
        __threadfence();
        __syncthreads();
        if (t == 0) arrive(&ctr[3]);
    }

    // stage E: all 1024 blocks broadcast o9[b][c] over the 4096 (w,h) slots
    if (t == 0) wait_ctr<16>(&ctr[3], 4);
    __syncthreads();
    __threadfence();
    float v = o9[bi];
    float4 vv = make_float4(v, v, v, v);
    float4* p = out + (size_t)bi * 1024;
    p[t]       = vv;
    p[t + 256] = vv;
    p[t + 512] = vv;
    p[t + 768] = vv;
}

extern "C" void kernel_launch(void* const* d_in, const int* in_sizes, int n_in,
                              void* d_out, int out_size, void* d_ws, size_t ws_size,
                              hipStream_t stream) {
    // 0:x 1:y 2:Wp 3:bp 4:W1 5:b1 6:W2 7:b2 8:Wq 9:bq 10:Wk 11:bk 12:Wv 13:bv 14:Wo 15:bo
    const float* y  = (const float*)d_in[1];
    const float* W1 = (const float*)d_in[4];
    const float* b1 = (const float*)d_in[5];
    const float* W2 = (const float*)d_in[6];
    const float* b2 = (const float*)d_in[7];
    const float* Wv = (const float*)d_in[12];
    const float* bv = (const float*)d_in[13];
    const float* Wo = (const float*)d_in[14];
    const float* bo = (const float*)d_in[15];

    float*    ws  = (float*)d_ws;
    unsigned* ctr = (unsigned*)((char*)d_ws + 32768);

    (void)hipMemsetAsync((void*)ctr, 0, 64, stream);  // zero barrier counters (capture-legal)
    mega<<<1024, 256, 0, stream>>>(y, W1, b1, W2, b2, Wv, bv, Wo, bo, ws, ctr, (float4*)d_out);
}

// Round 5
// 29.680 us; speedup vs baseline: 14.7973x; 14.7973x over previous
//
#include <hip/hip_runtime.h>

// BoxCrossAttention: softmax over a length-1 key axis == 1.0, so
// out[b,c,w,h] = 9 * (vp[b] @ Wo + bo)[c],  vp = (mish(y@W1+b1)@W2+b2)[:,512:] @ Wv + bv.
// x / conv / unfold / q / k projections are dead code.
//
// Round-4 post-mortem: 1024-block spin-barrier mega-kernel = 439us (agent-scope
// fence/poll storms across non-coherent XCD L2s). Reverting to multi-kernel.
// This round: shorten the chain algebraically. Everything after mish is linear:
//   o9 = v_raw @ (9*Wv@Wo) + 9*(bv@Wo + bo) = v_raw @ M9 + cvec
// M9/cvec depend only on weights -> computed in K1 in parallel with `hidden`
// (disjoint blocks). 3 kernels: K1{hidden || M9,cvec}, K2{v_raw}, K3{o9+bcast}.
// Fallback to the proven 4-kernel path if ws_size < 560KB.

__device__ __forceinline__ float mishf(float v) {
    float sp = (v > 20.0f) ? v : log1pf(expf(v));
    return v * tanhf(sp);
}

// ---------------- K1: hidden (blocks 0..63) || M9 (64..191) || cvec (192) ----
__global__ __launch_bounds__(256) void k1_fused(
    const float* __restrict__ y,  const float* __restrict__ W1, const float* __restrict__ b1,
    const float* __restrict__ Wv, const float* __restrict__ bv,
    const float* __restrict__ Wo, const float* __restrict__ bo,
    float* __restrict__ hidden, float* __restrict__ M9, float* __restrict__ cvec)
{
    __shared__ float smem[1024];
    int bi = blockIdx.x, t = threadIdx.x;

    if (bi < 64) {
        // hidden[b][j] = mish(b1[j] + sum_t y[b][t]*W1[t][j])
        int b = bi >> 4, j0 = (bi & 15) * 64;
        float* y_s = smem, * ps = smem + 256;
        y_s[t] = y[b * 256 + t];
        __syncthreads();
        int col = j0 + (t & 63), kc = t >> 6;
        const float* w  = W1 + (size_t)(kc * 64) * 1024 + col;
        const float* ys = y_s + kc * 64;
        float a0 = 0, a1 = 0, a2 = 0, a3 = 0;
        for (int r = 0; r < 64; r += 4) {
            a0 = fmaf(ys[r + 0], w[(r + 0) * 1024], a0);
            a1 = fmaf(ys[r + 1], w[(r + 1) * 1024], a1);
            a2 = fmaf(ys[r + 2], w[(r + 2) * 1024], a2);
            a3 = fmaf(ys[r + 3], w[(r + 3) * 1024], a3);
        }
        ps[t] = (a0 + a1) + (a2 + a3);
        __syncthreads();
        if (t < 64)
            hidden[b * 1024 + j0 + t] =
                mishf((ps[t] + ps[t + 64]) + (ps[t + 128] + ps[t + 192]) + b1[j0 + t]);
    } else if (bi < 192) {
        // M9[i][c] = 9 * sum_d Wv[i][d]*Wo[d][c]; 4 rows per block, c = t
        int i0 = (bi - 64) * 4;
        smem[t]       = Wv[(size_t)i0 * 256 + t];
        smem[t + 256] = Wv[(size_t)i0 * 256 + 256 + t];
        smem[t + 512] = Wv[(size_t)i0 * 256 + 512 + t];
        smem[t + 768] = Wv[(size_t)i0 * 256 + 768 + t];
        __syncthreads();
        const float* wo = Wo + t;
        float a0 = 0, a1 = 0, a2 = 0, a3 = 0;
        #pragma unroll 4
        for (int d = 0; d < 256; ++d) {
            float w = wo[(size_t)d * 256];          // coalesced across t
            a0 = fmaf(smem[d],       w, a0);        // LDS broadcast reads
            a1 = fmaf(smem[d + 256], w, a1);
            a2 = fmaf(smem[d + 512], w, a2);
            a3 = fmaf(smem[d + 768], w, a3);
        }
        M9[(size_t)(i0 + 0) * 256 + t] = 9.0f * a0;
        M9[(size_t)(i0 + 1) * 256 + t] = 9.0f * a1;
        M9[(size_t)(i0 + 2) * 256 + t] = 9.0f * a2;
        M9[(size_t)(i0 + 3) * 256 + t] = 9.0f * a3;
    } else {
        // cvec[c] = 9*(bo[c] + sum_d bv[d]*Wo[d][c])
        smem[t] = bv[t];
        __syncthreads();
        const float* wo = Wo + t;
        float a = 0;
        #pragma unroll 4
        for (int d = 0; d < 256; ++d) a = fmaf(smem[d], wo[(size_t)d * 256], a);
        cvec[t] = 9.0f * (a + bo[t]);
    }
}

// ---------------- K2: v_raw[b][c] = b2[512+c] + sum_i hidden[b][i]*W2[i][512+c]
__global__ __launch_bounds__(256) void k_vraw(const float* __restrict__ hidden,
                                              const float* __restrict__ W2,
                                              const float* __restrict__ b2,
                                              float* __restrict__ v_raw) {
    int b  = blockIdx.x >> 5;
    int c0 = (blockIdx.x & 31) * 16;
    int t  = threadIdx.x;
    int col = c0 + (t & 15);
    int kc  = t >> 4;
    __shared__ float h_s[1024];
    __shared__ float ps[256];
    h_s[t]       = hidden[b * 1024 + t];
    h_s[t + 256] = hidden[b * 1024 + t + 256];
    h_s[t + 512] = hidden[b * 1024 + t + 512];
    h_s[t + 768] = hidden[b * 1024 + t + 768];
    __syncthreads();
    const float* w  = W2 + (size_t)(kc * 64) * 1024 + 512 + col;
    const float* hs = h_s + kc * 64;
    float a0 = 0, a1 = 0, a2 = 0, a3 = 0;
    for (int r = 0; r < 64; r += 4) {
        a0 = fmaf(hs[r + 0], w[(size_t)(r + 0) * 1024], a0);
        a1 = fmaf(hs[r + 1], w[(size_t)(r + 1) * 1024], a1);
        a2 = fmaf(hs[r + 2], w[(size_t)(r + 2) * 1024], a2);
        a3 = fmaf(hs[r + 3], w[(size_t)(r + 3) * 1024], a3);
    }
    ps[t] = (a0 + a1) + (a2 + a3);
    __syncthreads();
    if (t < 16) {
        float s = 0;
        #pragma unroll
        for (int k = 0; k < 16; ++k) s += ps[t + 16 * k];
        v_raw[b * 512 + c0 + t] = s + b2[512 + c0 + t];
    }
}

// ---------------- K3: o9[b][c] = cvec[c] + v_raw[b] . M9[:,c]; broadcast-write.
// grid 256 = b(4) x 64 col-groups of 4. Block writes 4 x 4096 floats.
__global__ __launch_bounds__(256) void k3_obcast(const float* __restrict__ v_raw,
                                                 const float* __restrict__ M9,
                                                 const float* __restrict__ cvec,
                                                 float4* __restrict__ out) {
    int bi = blockIdx.x, t = threadIdx.x;
    int b = bi >> 6, c0 = (bi & 63) * 4;
    __shared__ float v_s[512];
    __shared__ float ps[256];
    __shared__ float o9s[4];
    v_s[t]       = v_raw[b * 512 + t];
    v_s[t + 256] = v_raw[b * 512 + t + 256];
    __syncthreads();
    int col = t & 3, kc = t >> 2;          // kc<64, 8 i's each
    int i0 = kc * 8;
    const float* m = M9 + c0 + col;
    float a0 = 0, a1 = 0;
    #pragma unroll
    for (int r = 0; r < 8; r += 2) {
        a0 = fmaf(v_s[i0 + r],     m[(size_t)(i0 + r) * 256],     a0);
        a1 = fmaf(v_s[i0 + r + 1], m[(size_t)(i0 + r + 1) * 256], a1);
    }
    ps[t] = a0 + a1;
    __syncthreads();
    if (t < 128) ps[t] += ps[t + 128];
    __syncthreads();
    if (t < 64) {
        float s = ps[t] + ps[t + 64];
        s += __shfl_down(s, 32);
        s += __shfl_down(s, 16);
        s += __shfl_down(s, 8);
        s += __shfl_down(s, 4);            // stays within col (shifts % 4 == 0)
        if (t < 4) o9s[t] = s + cvec[c0 + t];
    }
    __syncthreads();
    float v = o9s[t >> 6];
    float4 vv = make_float4(v, v, v, v);
    float4* p = out + (size_t)(b * 256 + c0 + (t >> 6)) * 1024;
    int l = t & 63;
    #pragma unroll
    for (int q = 0; q < 16; ++q) p[l + q * 64] = vv;
}

// ---------------- fallback path (proven round-2 kernels) ----------------
__global__ __launch_bounds__(256) void k_hidden(const float* __restrict__ y,
                                                const float* __restrict__ W1,
                                                const float* __restrict__ b1,
                                                float* __restrict__ hidden) {
    int b  = blockIdx.x >> 4;
    int j0 = (blockIdx.x & 15) * 64;
    int t  = threadIdx.x;
    int col = j0 + (t & 63);
    int kc  = t >> 6;
    __shared__ float y_s[256];
    __shared__ float ps[256];
    y_s[t] = y[b * 256 + t];
    __syncthreads();
    const float* w  = W1 + (size_t)(kc * 64) * 1024 + col;
    const float* ys = y_s + kc * 64;
    float a0 = 0, a1 = 0, a2 = 0, a3 = 0;
    for (int r = 0; r < 64; r += 4) {
        a0 = fmaf(ys[r + 0], w[(r + 0) * 1024], a0);
        a1 = fmaf(ys[r + 1], w[(r + 1) * 1024], a1);
        a2 = fmaf(ys[r + 2], w[(r + 2) * 1024], a2);
        a3 = fmaf(ys[r + 3], w[(r + 3) * 1024], a3);
    }
    ps[t] = (a0 + a1) + (a2 + a3);
    __syncthreads();
    if (t < 64)
        hidden[b * 1024 + j0 + t] =
            mishf((ps[t] + ps[t + 64]) + (ps[t + 128] + ps[t + 192]) + b1[j0 + t]);
}

__global__ __launch_bounds__(256) void k_vp(const float* __restrict__ v_raw,
                                            const float* __restrict__ Wv,
                                            const float* __restrict__ bv,
                                            float* __restrict__ vp) {
    int b  = blockIdx.x >> 3;
    int d0 = (blockIdx.x & 7) * 32;
    int t  = threadIdx.x;
    int col = d0 + (t & 31), kc = t >> 5;
    __shared__ float v_s[512];
    __shared__ float ps[256];
    v_s[t]       = v_raw[b * 512 + t];
    v_s[t + 256] = v_raw[b * 512 + t + 256];
    __syncthreads();
    const float* w  = Wv + (size_t)(kc * 64) * 256 + col;
    const float* vs = v_s + kc * 64;
    float a0 = 0, a1 = 0, a2 = 0, a3 = 0;
    for (int r = 0; r < 64; r += 4) {
        a0 = fmaf(vs[r + 0], w[(r + 0) * 256], a0);
        a1 = fmaf(vs[r + 1], w[(r + 1) * 256], a1);
        a2 = fmaf(vs[r + 2], w[(r + 2) * 256], a2);
        a3 = fmaf(vs[r + 3], w[(r + 3) * 256], a3);
    }
    ps[t] = (a0 + a1) + (a2 + a3);
    __syncthreads();
    if (t < 32) {
        float s = 0;
        #pragma unroll
        for (int k = 0; k < 8; ++k) s += ps[t + 32 * k];
        vp[b * 256 + d0 + t] = s + bv[d0 + t];
    }
}

__global__ __launch_bounds__(256) void k_out(const float* __restrict__ vp,
                                             const float* __restrict__ Wo,
                                             const float* __restrict__ bo,
                                             float4* __restrict__ out) {
    int b = blockIdx.x >> 8, c = blockIdx.x & 255, t = threadIdx.x;
    __shared__ float red[256];
    red[t] = vp[b * 256 + t] * Wo[(size_t)t * 256 + c];
    __syncthreads();
    if (t < 64) {
        float s = (red[t] + red[t + 64]) + (red[t + 128] + red[t + 192]);
        s += __shfl_down(s, 32);
        s += __shfl_down(s, 16);
        s += __shfl_down(s, 8);
        s += __shfl_down(s, 4);
        s += __shfl_down(s, 2);
        s += __shfl_down(s, 1);
        if (t == 0) red[0] = 9.0f * (s + bo[c]);
    }
    __syncthreads();
    float v = red[0];
    float4 vv = make_float4(v, v, v, v);
    float4* p = out + (size_t)blockIdx.x * 1024;
    p[t]       = vv;
    p[t + 256] = vv;
    p[t + 512] = vv;
    p[t + 768] = vv;
}

extern "C" void kernel_launch(void* const* d_in, const int* in_sizes, int n_in,
                              void* d_out, int out_size, void* d_ws, size_t ws_size,
                              hipStream_t stream) {
    // 0:x 1:y 2:Wp 3:bp 4:W1 5:b1 6:W2 7:b2 8:Wq 9:bq 10:Wk 11:bk 12:Wv 13:bv 14:Wo 15:bo
    const float* y  = (const float*)d_in[1];
    const float* W1 = (const float*)d_in[4];
    const float* b1 = (const float*)d_in[5];
    const float* W2 = (const float*)d_in[6];
    const float* b2 = (const float*)d_in[7];
    const float* Wv = (const float*)d_in[12];
    const float* bv = (const float*)d_in[13];
    const float* Wo = (const float*)d_in[14];
    const float* bo = (const float*)d_in[15];

    float* ws     = (float*)d_ws;
    float* hidden = ws;           // 4096 floats
    float* v_raw  = ws + 4096;    // 2048
    float* M9     = ws + 8192;    // 131072 (512KB)
    float* cvec   = ws + 139264;  // 256
    const size_t need = (size_t)139520 * 4;

    if (ws_size >= need) {
        k1_fused <<<193, 256, 0, stream>>>(y, W1, b1, Wv, bv, Wo, bo, hidden, M9, cvec);
        k_vraw   <<<128, 256, 0, stream>>>(hidden, W2, b2, v_raw);
        k3_obcast<<<256, 256, 0, stream>>>(v_raw, M9, cvec, (float4*)d_out);
    } else {
        float* vp = ws + 6144;    // 1024
        k_hidden<<<64,   256, 0, stream>>>(y, W1, b1, hidden);
        k_vraw  <<<128,  256, 0, stream>>>(hidden, W2, b2, v_raw);
        k_vp    <<<32,   256, 0, stream>>>(v_raw, Wv, bv, vp);
        k_out   <<<1024, 256, 0, stream>>>(vp, Wo, bo, (float4*)d_out);
    }
}

// Round 6
// 19.943 us; speedup vs baseline: 22.0224x; 1.4883x over previous
//
#include <hip/hip_runtime.h>

// BoxCrossAttention: softmax over a length-1 key axis == 1.0, so
// out[b,c,w,h] = 9 * (vp[b] @ Wo + bo)[c],  vp = (mish(y@W1+b1)@W2+b2)[:,512:] @ Wv + bv.
// x / conv / unfold / q / k projections are dead code.
//
// R4: global spin-sync mega-kernel = 439us (fence/poll storm) — dead end.
// R5: M9=Wv@Wo folding = 29.7us — M9 is 33M MACs, 8x the live network. Dead end.
// R6: round-2 structure (21us) minus one node: k_vraw blocks also emit their
// 16-row partial outer-product contribution to vp (vp_part[block][256], no
// atomics, Wv read once total); final kernel sums 32 partials in its prologue.
// 3 nodes: K1 hidden -> K2 v_raw+vp_part -> K3 o9+broadcast.

__device__ __forceinline__ float mishf(float v) {
    float sp = (v > 20.0f) ? v : log1pf(expf(v));
    return v * tanhf(sp);
}

// K1: hidden[b][j] = mish(b1[j] + sum_t y[b][t]*W1[t][j]); grid 64
__global__ __launch_bounds__(256) void k_hidden(const float* __restrict__ y,
                                                const float* __restrict__ W1,
                                                const float* __restrict__ b1,
                                                float* __restrict__ hidden) {
    int b  = blockIdx.x >> 4;
    int j0 = (blockIdx.x & 15) * 64;
    int t  = threadIdx.x;
    int col = j0 + (t & 63);
    int kc  = t >> 6;
    __shared__ float y_s[256];
    __shared__ float ps[256];
    y_s[t] = y[b * 256 + t];
    __syncthreads();
    const float* w  = W1 + (size_t)(kc * 64) * 1024 + col;
    const float* ys = y_s + kc * 64;
    float a0 = 0, a1 = 0, a2 = 0, a3 = 0;
    for (int r = 0; r < 64; r += 4) {
        a0 = fmaf(ys[r + 0], w[(r + 0) * 1024], a0);
        a1 = fmaf(ys[r + 1], w[(r + 1) * 1024], a1);
        a2 = fmaf(ys[r + 2], w[(r + 2) * 1024], a2);
        a3 = fmaf(ys[r + 3], w[(r + 3) * 1024], a3);
    }
    ps[t] = (a0 + a1) + (a2 + a3);
    __syncthreads();
    if (t < 64)
        hidden[b * 1024 + j0 + t] =
            mishf((ps[t] + ps[t + 64]) + (ps[t + 128] + ps[t + 192]) + b1[j0 + t]);
}

// K2: v_raw[b][c] for 16 cols, then this block's vp partial:
// vp_part[blockIdx][d] = sum_{k<16} v_raw[b][c0+k] * Wv[c0+k][d].  grid 128.
__global__ __launch_bounds__(256) void k_vraw_vppart(const float* __restrict__ hidden,
                                                     const float* __restrict__ W2,
                                                     const float* __restrict__ b2,
                                                     const float* __restrict__ Wv,
                                                     float* __restrict__ vp_part) {
    int b  = blockIdx.x >> 5;
    int c0 = (blockIdx.x & 31) * 16;
    int t  = threadIdx.x;
    int col = c0 + (t & 15);
    int kc  = t >> 4;
    __shared__ float h_s[1024];
    __shared__ float ps[256];
    __shared__ float vr16[16];
    h_s[t]       = hidden[b * 1024 + t];
    h_s[t + 256] = hidden[b * 1024 + t + 256];
    h_s[t + 512] = hidden[b * 1024 + t + 512];
    h_s[t + 768] = hidden[b * 1024 + t + 768];
    __syncthreads();
    const float* w  = W2 + (size_t)(kc * 64) * 1024 + 512 + col;
    const float* hs = h_s + kc * 64;
    float a0 = 0, a1 = 0, a2 = 0, a3 = 0;
    for (int r = 0; r < 64; r += 4) {
        a0 = fmaf(hs[r + 0], w[(size_t)(r + 0) * 1024], a0);
        a1 = fmaf(hs[r + 1], w[(size_t)(r + 1) * 1024], a1);
        a2 = fmaf(hs[r + 2], w[(size_t)(r + 2) * 1024], a2);
        a3 = fmaf(hs[r + 3], w[(size_t)(r + 3) * 1024], a3);
    }
    ps[t] = (a0 + a1) + (a2 + a3);
    __syncthreads();
    if (t < 16) {
        float s = 0;
        #pragma unroll
        for (int k = 0; k < 16; ++k) s += ps[t + 16 * k];
        vr16[t] = s + b2[512 + c0 + t];
    }
    __syncthreads();
    // partial outer product: 16 MACs/thread, Wv rows c0..c0+15, coalesced in t
    const float* wv = Wv + (size_t)c0 * 256 + t;
    float acc0 = 0, acc1 = 0;
    #pragma unroll
    for (int k = 0; k < 16; k += 2) {
        acc0 = fmaf(vr16[k],     wv[(k + 0) * 256], acc0);
        acc1 = fmaf(vr16[k + 1], wv[(k + 1) * 256], acc1);
    }
    vp_part[(size_t)blockIdx.x * 256 + t] = acc0 + acc1;
}

// K3: block (b,c): vp[t] = sum_{p<32} vp_part[b*32+p][t] + bv[t];
// o9 = 9*(dot(vp, Wo[:,c]) + bo[c]); broadcast over 4096 slots. grid 1024.
__global__ __launch_bounds__(256) void k_out3(const float* __restrict__ vp_part,
                                              const float* __restrict__ bv,
                                              const float* __restrict__ Wo,
                                              const float* __restrict__ bo,
                                              float4* __restrict__ out) {
    int b = blockIdx.x >> 8, c = blockIdx.x & 255, t = threadIdx.x;
    __shared__ float red[256];
    const float* vpp = vp_part + (size_t)b * 32 * 256 + t;
    float s0 = 0, s1 = 0, s2 = 0, s3 = 0;
    #pragma unroll
    for (int p = 0; p < 32; p += 4) {
        s0 += vpp[(p + 0) * 256];
        s1 += vpp[(p + 1) * 256];
        s2 += vpp[(p + 2) * 256];
        s3 += vpp[(p + 3) * 256];
    }
    float vpv = ((s0 + s1) + (s2 + s3)) + bv[t];
    red[t] = vpv * Wo[(size_t)t * 256 + c];
    __syncthreads();
    if (t < 64) {
        float s = (red[t] + red[t + 64]) + (red[t + 128] + red[t + 192]);
        s += __shfl_down(s, 32);
        s += __shfl_down(s, 16);
        s += __shfl_down(s, 8);
        s += __shfl_down(s, 4);
        s += __shfl_down(s, 2);
        s += __shfl_down(s, 1);
        if (t == 0) red[0] = 9.0f * (s + bo[c]);
    }
    __syncthreads();
    float v = red[0];
    float4 vv = make_float4(v, v, v, v);
    float4* p = out + (size_t)blockIdx.x * 1024;
    p[t]       = vv;
    p[t + 256] = vv;
    p[t + 512] = vv;
    p[t + 768] = vv;
}

// ---------------- fallback (proven round-2 kernels, 28KB ws) ----------------
__global__ __launch_bounds__(256) void k_vraw(const float* __restrict__ hidden,
                                              const float* __restrict__ W2,
                                              const float* __restrict__ b2,
                                              float* __restrict__ v_raw) {
    int b  = blockIdx.x >> 5;
    int c0 = (blockIdx.x & 31) * 16;
    int t  = threadIdx.x;
    int col = c0 + (t & 15);
    int kc  = t >> 4;
    __shared__ float h_s[1024];
    __shared__ float ps[256];
    h_s[t]       = hidden[b * 1024 + t];
    h_s[t + 256] = hidden[b * 1024 + t + 256];
    h_s[t + 512] = hidden[b * 1024 + t + 512];
    h_s[t + 768] = hidden[b * 1024 + t + 768];
    __syncthreads();
    const float* w  = W2 + (size_t)(kc * 64) * 1024 + 512 + col;
    const float* hs = h_s + kc * 64;
    float a0 = 0, a1 = 0, a2 = 0, a3 = 0;
    for (int r = 0; r < 64; r += 4) {
        a0 = fmaf(hs[r + 0], w[(size_t)(r + 0) * 1024], a0);
        a1 = fmaf(hs[r + 1], w[(size_t)(r + 1) * 1024], a1);
        a2 = fmaf(hs[r + 2], w[(size_t)(r + 2) * 1024], a2);
        a3 = fmaf(hs[r + 3], w[(size_t)(r + 3) * 1024], a3);
    }
    ps[t] = (a0 + a1) + (a2 + a3);
    __syncthreads();
    if (t < 16) {
        float s = 0;
        #pragma unroll
        for (int k = 0; k < 16; ++k) s += ps[t + 16 * k];
        v_raw[b * 512 + c0 + t] = s + b2[512 + c0 + t];
    }
}

__global__ __launch_bounds__(256) void k_vp(const float* __restrict__ v_raw,
                                            const float* __restrict__ Wv,
                                            const float* __restrict__ bv,
                                            float* __restrict__ vp) {
    int b  = blockIdx.x >> 3;
    int d0 = (blockIdx.x & 7) * 32;
    int t  = threadIdx.x;
    int col = d0 + (t & 31), kc = t >> 5;
    __shared__ float v_s[512];
    __shared__ float ps[256];
    v_s[t]       = v_raw[b * 512 + t];
    v_s[t + 256] = v_raw[b * 512 + t + 256];
    __syncthreads();
    const float* w  = Wv + (size_t)(kc * 64) * 256 + col;
    const float* vs = v_s + kc * 64;
    float a0 = 0, a1 = 0, a2 = 0, a3 = 0;
    for (int r = 0; r < 64; r += 4) {
        a0 = fmaf(vs[r + 0], w[(r + 0) * 256], a0);
        a1 = fmaf(vs[r + 1], w[(r + 1) * 256], a1);
        a2 = fmaf(vs[r + 2], w[(r + 2) * 256], a2);
        a3 = fmaf(vs[r + 3], w[(r + 3) * 256], a3);
    }
    ps[t] = (a0 + a1) + (a2 + a3);
    __syncthreads();
    if (t < 32) {
        float s = 0;
        #pragma unroll
        for (int k = 0; k < 8; ++k) s += ps[t + 32 * k];
        vp[b * 256 + d0 + t] = s + bv[d0 + t];
    }
}

__global__ __launch_bounds__(256) void k_out(const float* __restrict__ vp,
                                             const float* __restrict__ Wo,
                                             const float* __restrict__ bo,
                                             float4* __restrict__ out) {
    int b = blockIdx.x >> 8, c = blockIdx.x & 255, t = threadIdx.x;
    __shared__ float red[256];
    red[t] = vp[b * 256 + t] * Wo[(size_t)t * 256 + c];
    __syncthreads();
    if (t < 64) {
        float s = (red[t] + red[t + 64]) + (red[t + 128] + red[t + 192]);
        s += __shfl_down(s, 32);
        s += __shfl_down(s, 16);
        s += __shfl_down(s, 8);
        s += __shfl_down(s, 4);
        s += __shfl_down(s, 2);
        s += __shfl_down(s, 1);
        if (t == 0) red[0] = 9.0f * (s + bo[c]);
    }
    __syncthreads();
    float v = red[0];
    float4 vv = make_float4(v, v, v, v);
    float4* p = out + (size_t)blockIdx.x * 1024;
    p[t]       = vv;
    p[t + 256] = vv;
    p[t + 512] = vv;
    p[t + 768] = vv;
}

extern "C" void kernel_launch(void* const* d_in, const int* in_sizes, int n_in,
                              void* d_out, int out_size, void* d_ws, size_t ws_size,
                              hipStream_t stream) {
    // 0:x 1:y 2:Wp 3:bp 4:W1 5:b1 6:W2 7:b2 8:Wq 9:bq 10:Wk 11:bk 12:Wv 13:bv 14:Wo 15:bo
    const float* y  = (const float*)d_in[1];
    const float* W1 = (const float*)d_in[4];
    const float* b1 = (const float*)d_in[5];
    const float* W2 = (const float*)d_in[6];
    const float* b2 = (const float*)d_in[7];
    const float* Wv = (const float*)d_in[12];
    const float* bv = (const float*)d_in[13];
    const float* Wo = (const float*)d_in[14];
    const float* bo = (const float*)d_in[15];

    float* ws      = (float*)d_ws;
    float* hidden  = ws;          // 4096 floats
    float* vp_part = ws + 4096;   // 128 blocks x 256 = 32768 floats
    const size_t need = (size_t)(4096 + 32768) * 4;   // 147KB

    if (ws_size >= need) {
        k_hidden     <<<64,   256, 0, stream>>>(y, W1, b1, hidden);
        k_vraw_vppart<<<128,  256, 0, stream>>>(hidden, W2, b2, Wv, vp_part);
        k_out3       <<<1024, 256, 0, stream>>>(vp_part, bv, Wo, bo, (float4*)d_out);
    } else {
        float* v_raw = ws + 4096;  // 2048
        float* vp    = ws + 6144;  // 1024
        k_hidden<<<64,   256, 0, stream>>>(y, W1, b1, hidden);
        k_vraw  <<<128,  256, 0, stream>>>(hidden, W2, b2, v_raw);
        k_vp    <<<32,   256, 0, stream>>>(v_raw, Wv, bv, vp);
        k_out   <<<1024, 256, 0, stream>>>(vp, Wo, bo, (float4*)d_out);
    }
}